// Round 1
// baseline (281.997 us; speedup 1.0000x reference)
//
#include <hip/hip_runtime.h>

#define B_ROWS 8192
#define D_IN   1024
#define NOUT   1024
#define NB     8
#define KTOT   (D_IN * (NB + 1))   // 9216
#define BM     128
#define BN     128
#define BK     64

typedef __attribute__((ext_vector_type(4))) float f32x4;
typedef __attribute__((ext_vector_type(8))) short bf16x8;

__device__ __forceinline__ unsigned short f2bf(float f) {
  union { float f; unsigned u; } v; v.f = f;
  unsigned r = v.u + 0x7fffu + ((v.u >> 16) & 1u);   // RNE
  return (unsigned short)(r >> 16);
}

__device__ __forceinline__ void load_lds16(const void* g, void* l) {
  __builtin_amdgcn_global_load_lds(
      (const __attribute__((address_space(1))) unsigned int*)g,
      (__attribute__((address_space(3))) unsigned int*)l, 16, 0, 0);
}

// ---------------- weights -> bf16, concatenated [NOUT][KTOT] ----------------
__global__ __launch_bounds__(256) void wconv_kernel(
    const float* __restrict__ bw, const float* __restrict__ sw,
    unsigned short* __restrict__ Wc) {
  const size_t idx = ((size_t)blockIdx.x * 256 + threadIdx.x) * 4;
  const int n = (int)(idx / KTOT);
  const int k = (int)(idx % KTOT);
  float4 f;
  if (k < D_IN)
    f = *reinterpret_cast<const float4*>(bw + (size_t)n * D_IN + k);
  else
    f = *reinterpret_cast<const float4*>(sw + (size_t)n * (D_IN * NB) + (k - D_IN));
  union { unsigned short us[4]; uint2 u2; } o;
  o.us[0] = f2bf(f.x); o.us[1] = f2bf(f.y); o.us[2] = f2bf(f.z); o.us[3] = f2bf(f.w);
  *reinterpret_cast<uint2*>(Wc + idx) = o.u2;
}

// ------------- LayerNorm + silu + (spline + rbf) feature matrix -------------
// F[row][0:1024]      = silu(xn)            (bf16)
// F[row][1024+8d+j]   = spl_j(xn_d) + rbf_j(xn_d)
__global__ __launch_bounds__(256) void feat_kernel(
    const float* __restrict__ x, const float* __restrict__ lnw,
    const float* __restrict__ lnb, unsigned short* __restrict__ F, int row0) {
  const int row = row0 + blockIdx.x;
  const float* xr = x + (size_t)row * D_IN;
  const int t = threadIdx.x;
  float v[4];
  float s = 0.f, s2 = 0.f;
#pragma unroll
  for (int i = 0; i < 4; ++i) {
    v[i] = xr[t + 256 * i];
    s += v[i];
    s2 += v[i] * v[i];
  }
#pragma unroll
  for (int off = 32; off > 0; off >>= 1) {
    s += __shfl_xor(s, off);
    s2 += __shfl_xor(s2, off);
  }
  __shared__ float red[8];
  const int wid = t >> 6;
  if ((t & 63) == 0) { red[wid] = s; red[4 + wid] = s2; }
  __syncthreads();
  s  = red[0] + red[1] + red[2] + red[3];
  s2 = red[4] + red[5] + red[6] + red[7];
  const float mu = s * (1.f / D_IN);
  const float var = s2 * (1.f / D_IN) - mu * mu;
  const float rstd = rsqrtf(var + 1e-5f);
  unsigned short* Frow = F + (size_t)blockIdx.x * KTOT;
#pragma unroll
  for (int i = 0; i < 4; ++i) {
    const int d = t + 256 * i;
    const float xn = (v[i] - mu) * rstd * lnw[d] + lnb[d];
    // SiLU
    Frow[d] = f2bf(xn / (1.f + __expf(-xn)));
    // cubic B-spline via de Boor on uniform knots g[j] = 0.6j - 3.3 (j=0..11)
    float b[11];
#pragma unroll
    for (int j = 0; j < 11; ++j) {
      const float gj = 0.6f * j - 3.3f;
      b[j] = (xn >= gj && xn < gj + 0.6f) ? 1.f : 0.f;
    }
#pragma unroll
    for (int k = 1; k <= 3; ++k) {
      const float inv = 1.f / (0.6f * k);
#pragma unroll
      for (int j = 0; j <= 10 - k; ++j) {
        const float gj = 0.6f * j - 3.3f;
        b[j] = (xn - gj) * inv * b[j] + (gj + 0.6f * (k + 1) - xn) * inv * b[j + 1];
      }
    }
    union { unsigned short us[8]; uint4 u4; } pk;
#pragma unroll
    for (int j = 0; j < 8; ++j) {
      const float c = -1.5f + (3.f / 7.f) * j;     // rbf centers, denom = 3/7
      const float tt = (xn - c) * (7.f / 3.f);
      pk.us[j] = f2bf(b[j] + __expf(-tt * tt));
    }
    *reinterpret_cast<uint4*>(Frow + D_IN + (size_t)d * 8) = pk.u4;
  }
}

// ------------------------- GEMM: C = F @ Wc^T (f32) -------------------------
// A = F [rows][KTOT] bf16 row-major, Bw = Wc [NOUT][KTOT] bf16 row-major.
__global__ __launch_bounds__(256) void gemm_kernel(
    const unsigned short* __restrict__ A, const unsigned short* __restrict__ Bw,
    float* __restrict__ C, int row0) {
  __shared__ unsigned short As[BM][BK];   // 16 KB
  __shared__ unsigned short Bs[BN][BK];   // 16 KB
  const int t = threadIdx.x;
  const int wid = t >> 6;
  const int lane = t & 63;
  const int wr = wid >> 1, wc = wid & 1;            // 2x2 waves -> 64x64 each
  f32x4 acc[4][4] = {};
  const size_t Abase = (size_t)blockIdx.x * BM * KTOT;
  const size_t Bbase = (size_t)blockIdx.y * BN * KTOT;
  const int r_ = t >> 3;     // chunk row within 32-row group
  const int c_ = t & 7;      // 16B chunk within row
  for (int k0 = 0; k0 < KTOT; k0 += BK) {
#pragma unroll
    for (int i = 0; i < 4; ++i) {
      const int r = i * 32 + r_;
      load_lds16(A + Abase + (size_t)r * KTOT + k0 + c_ * 8,
                 (char*)&As[0][0] + i * 4096 + wid * 1024);
      load_lds16(Bw + Bbase + (size_t)r * KTOT + k0 + c_ * 8,
                 (char*)&Bs[0][0] + i * 4096 + wid * 1024);
    }
    asm volatile("s_waitcnt vmcnt(0)" ::: "memory");
    __syncthreads();
#pragma unroll
    for (int kk = 0; kk < BK / 32; ++kk) {
      bf16x8 a[4], b[4];
      const int kof = kk * 32 + (lane >> 4) * 8;
#pragma unroll
      for (int m = 0; m < 4; ++m)
        a[m] = *reinterpret_cast<const bf16x8*>(&As[wr * 64 + m * 16 + (lane & 15)][kof]);
#pragma unroll
      for (int n = 0; n < 4; ++n)
        b[n] = *reinterpret_cast<const bf16x8*>(&Bs[wc * 64 + n * 16 + (lane & 15)][kof]);
#pragma unroll
      for (int m = 0; m < 4; ++m)
#pragma unroll
        for (int n = 0; n < 4; ++n)
          acc[m][n] = __builtin_amdgcn_mfma_f32_16x16x32_bf16(a[m], b[n], acc[m][n], 0, 0, 0);
    }
    __syncthreads();
  }
  const int crow0 = row0 + blockIdx.x * BM + wr * 64 + (lane >> 4) * 4;
  const int ccol0 = blockIdx.y * BN + wc * 64 + (lane & 15);
#pragma unroll
  for (int m = 0; m < 4; ++m)
#pragma unroll
    for (int n = 0; n < 4; ++n) {
      float* cp = C + (size_t)(crow0 + m * 16) * NOUT + ccol0 + n * 16;
#pragma unroll
      for (int r = 0; r < 4; ++r)
        cp[(size_t)r * NOUT] = acc[m][n][r];
    }
}

extern "C" void kernel_launch(void* const* d_in, const int* in_sizes, int n_in,
                              void* d_out, int out_size, void* d_ws, size_t ws_size,
                              hipStream_t stream) {
  const float* x   = (const float*)d_in[0];
  const float* lnw = (const float*)d_in[1];
  const float* lnb = (const float*)d_in[2];
  const float* bw  = (const float*)d_in[3];
  const float* sw  = (const float*)d_in[4];
  float* out = (float*)d_out;
  char* ws = (char*)d_ws;

  const size_t wc_bytes = (size_t)NOUT * KTOT * 2;           // ~18.9 MB
  unsigned short* Wc = (unsigned short*)ws;
  unsigned short* F  = (unsigned short*)(ws + wc_bytes);

  // chunk M so Wc + F fit in workspace (deterministic in ws_size)
  size_t avail = (ws_size > wc_bytes) ? ws_size - wc_bytes : 0;
  long long cm = (long long)(avail / ((size_t)KTOT * 2));
  cm &= ~127LL;
  if (cm < 128) cm = 128;
  if (cm > B_ROWS) cm = B_ROWS;
  const int chunkM = (int)cm;

  wconv_kernel<<<(NOUT * (KTOT / 4)) / 256, 256, 0, stream>>>(bw, sw, Wc);
  for (int r0 = 0; r0 < B_ROWS; r0 += chunkM) {
    int rows = B_ROWS - r0; if (rows > chunkM) rows = chunkM;
    feat_kernel<<<rows, 256, 0, stream>>>(x, lnw, lnb, F, r0);
    gemm_kernel<<<dim3(rows / BM, NOUT / BN), 256, 0, stream>>>(F, Wc, out, r0);
  }
}